// Round 5
// baseline (258.757 us; speedup 1.0000x reference)
//
#include <hip/hip_runtime.h>
#include <stdint.h>

typedef unsigned short u16;
typedef short bf16x8 __attribute__((ext_vector_type(8)));   // 8 bf16 in 4 VGPRs
typedef float f32x4 __attribute__((ext_vector_type(4)));

typedef void as1_void __attribute__((address_space(1)));
typedef void as3_void __attribute__((address_space(3)));

__device__ inline u16 f32_to_bf16(float f) {
    uint32_t u = __builtin_bit_cast(uint32_t, f);
    u += 0x7fffu + ((u >> 16) & 1u);   // RNE (finite values only)
    return (u16)(u >> 16);
}

__device__ inline void gld_lds16(const void* g, void* l) {
    // async global->LDS, 16B/lane; HW dest = wave-uniform base + lane*16
    __builtin_amdgcn_global_load_lds((as1_void*)g, (as3_void*)l, 16, 0, 0);
}

// LDS tile layout (both GEMMs): 128 rows x 64 cols bf16 as 1024 chunks of 16B.
// (row, colchunk j) -> chunk slot row*8 + (j ^ (row&7)).  XOR swizzle => frag
// reads hit all 32 banks at <=2-way aliasing (free, m136); staging stays
// lane-contiguous for global_load_lds / b128 writes.

// ---------------- fused prep kernel #1 ----------------
// blocks [0, 24576): x/h_prev f32 -> bf16 contiguous cast into {x_bf | hp_bf}
// blocks [24576, 28672): Bcat[c][colOff+r] = bf16(Br/Bi[r][c]) 32x32 transpose

__global__ void bigcast_kernel(const float* __restrict__ x,
                               const float* __restrict__ h_prev,
                               const float* __restrict__ Br,
                               const float* __restrict__ Bi,
                               u16* __restrict__ xh_bf,
                               u16* __restrict__ Bcat) {
    const int n4x = 8192 * 1024 / 4;     // 2097152
    const int tid = threadIdx.x;
    if (blockIdx.x < 24576) {
        int i = blockIdx.x * 256 + tid;
        float4 f = (i < n4x) ? ((const float4*)x)[i] : ((const float4*)h_prev)[i - n4x];
        ushort4 o;
        o.x = f32_to_bf16(f.x); o.y = f32_to_bf16(f.y);
        o.z = f32_to_bf16(f.z); o.w = f32_to_bf16(f.w);
        ((ushort4*)xh_bf)[i] = o;
    } else {
        __shared__ float t[32][33];
        int id2 = blockIdx.x - 24576;
        const float* src = (id2 >= 2048) ? Bi : Br;
        int colOff = (id2 >= 2048) ? 2048 : 0;
        int rem = id2 & 2047;
        int c0 = (rem & 31) * 32, r0 = (rem >> 5) * 32;
        int tx = tid & 31, ty = tid >> 5;      // 32 x 8
#pragma unroll
        for (int j = 0; j < 4; j++)
            t[ty + j * 8][tx] = src[(size_t)(r0 + ty + j * 8) * 1024 + c0 + tx];
        __syncthreads();
#pragma unroll
        for (int j = 0; j < 4; j++)
            Bcat[(size_t)(c0 + ty + j * 8) * 4096 + colOff + r0 + tx] =
                f32_to_bf16(t[tx][ty + j * 8]);
    }
}

// ---------------- fused prep kernel #2 ----------------
// [region A] Wmain[o][c] = bf16(sum_z partials[z][o][c])
// [region B] Cwbf[o][h]  = bf16(Cr*wr - Ci*wi), w recomputed inline from v_log/theta_log

__global__ void reduce_cw_kernel(const float* __restrict__ partials,
                                 const float* __restrict__ Cr, const float* __restrict__ Ci,
                                 const float* __restrict__ v_log, const float* __restrict__ th_log,
                                 u16* __restrict__ Wmain, u16* __restrict__ Cwbf) {
    const int n4_red = 1024 * 1024 / 4;
    const int n4_cw  = 1024 * 2048 / 4;
    int i = blockIdx.x * blockDim.x + threadIdx.x;
    if (i < n4_red) {
        int e = i * 4;
        float4 s = *(const float4*)(partials + e);
#pragma unroll
        for (int z = 1; z < 8; z++) {
            float4 p = *(const float4*)(partials + ((size_t)z << 20) + e);
            s.x += p.x; s.y += p.y; s.z += p.z; s.w += p.w;
        }
        ushort4 u;
        u.x = f32_to_bf16(s.x); u.y = f32_to_bf16(s.y);
        u.z = f32_to_bf16(s.z); u.w = f32_to_bf16(s.w);
        ((ushort4*)Wmain)[i] = u;
    } else if (i < n4_red + n4_cw) {
        int j = i - n4_red;
        int e = j * 4;
        int o = e >> 11;
        int h = e & 2047;
        float4 cr = *(const float4*)(Cr + (size_t)o * 2048 + h);
        float4 ci = *(const float4*)(Ci + (size_t)o * 2048 + h);
        float4 vl = *(const float4*)(v_log + h);
        float4 tl = *(const float4*)(th_log + h);
        float mag, ang;
        ushort4 u;
        mag = expf(-expf(vl.x)); ang = expf(tl.x);
        u.x = f32_to_bf16(cr.x * (mag * cosf(ang)) - ci.x * (mag * sinf(ang)));
        mag = expf(-expf(vl.y)); ang = expf(tl.y);
        u.y = f32_to_bf16(cr.y * (mag * cosf(ang)) - ci.y * (mag * sinf(ang)));
        mag = expf(-expf(vl.z)); ang = expf(tl.z);
        u.z = f32_to_bf16(cr.z * (mag * cosf(ang)) - ci.z * (mag * sinf(ang)));
        mag = expf(-expf(vl.w)); ang = expf(tl.w);
        u.w = f32_to_bf16(cr.w * (mag * cosf(ang)) - ci.w * (mag * sinf(ang)));
        ((ushort4*)Cwbf)[j] = u;
    }
}

// ---------------- weight GEMM: split-K=8, 128x128 tile, BK=64 ----------------
// partials[bz][m][n] = sum_k A[m][k]*Bcat[n][k] over k-slice bz*512..+512, where
// A[m][k] = Cr[m][k] (k<2048) / -Ci[m][k-2048] — staged from f32 with in-kernel
// bf16 pack (kills the pack_ccat kernel). B staged async from prebuilt Bcat.

__global__ __launch_bounds__(256)
void gemm_splitk_kernel(const float* __restrict__ Cr, const float* __restrict__ Ci,
                        const u16* __restrict__ Bcat, float* __restrict__ partials)
{
    __shared__ __align__(16) u16 ldsA[128 * 64];
    __shared__ __align__(16) u16 ldsB[128 * 64];

    const int tid = threadIdx.x, wid = tid >> 6, lane = tid & 63;
    const int quad = lane >> 4, l16 = lane & 15;
    const int wm = wid >> 1, wn = wid & 1;
    const int bm = blockIdx.y, bn = blockIdx.x, bz = blockIdx.z;

    // A source: block-uniform matrix + sign
    const float* Asrc = (bz < 4) ? Cr : Ci;
    const uint32_t sgn_mask = (bz < 4) ? 0u : 0x80000000u;
    const int akb = (bz < 4) ? bz * 512 : bz * 512 - 2048;

    // A staging: thread covers row ar, 32 k-elems starting at ac
    const int ar = tid >> 1;
    const int ac = (tid & 1) * 32;
    const float* agp = Asrc + (size_t)(bm * 128 + ar) * 2048 + akb + ac;

    // B staging (async DMA)
    const u16* gB[4];
    u16* lB[4];
#pragma unroll
    for (int t = 0; t < 4; t++) {
        int s = wid * 256 + t * 64 + lane;
        int sr = s >> 3;
        int sj = (s & 7) ^ (sr & 7);
        lB[t] = ldsB + s * 8;
        gB[t] = Bcat + (size_t)(bn * 128 + sr) * 4096 + sj * 8 + bz * 512;
    }

    const f32x4 fz = {0.f, 0.f, 0.f, 0.f};
    f32x4 acc[4][4];
#pragma unroll
    for (int i = 0; i < 4; i++)
#pragma unroll
        for (int j = 0; j < 4; j++) acc[i][j] = fz;

    for (int k0 = 0; k0 < 512; k0 += 64) {
        __syncthreads();
#pragma unroll
        for (int t = 0; t < 4; t++)
            gld_lds16(gB[t] + k0, lB[t]);
        // A: 8 float4 loads -> 4 swizzled 16B LDS chunks
        float4 av[8];
#pragma unroll
        for (int q = 0; q < 8; q++)
            av[q] = *(const float4*)(agp + k0 + q * 4);
#pragma unroll
        for (int c = 0; c < 4; c++) {
            bf16x8 w;
            const float4 a0 = av[2 * c], a1 = av[2 * c + 1];
            w[0] = (short)f32_to_bf16(__builtin_bit_cast(float, __builtin_bit_cast(uint32_t, a0.x) ^ sgn_mask));
            w[1] = (short)f32_to_bf16(__builtin_bit_cast(float, __builtin_bit_cast(uint32_t, a0.y) ^ sgn_mask));
            w[2] = (short)f32_to_bf16(__builtin_bit_cast(float, __builtin_bit_cast(uint32_t, a0.z) ^ sgn_mask));
            w[3] = (short)f32_to_bf16(__builtin_bit_cast(float, __builtin_bit_cast(uint32_t, a0.w) ^ sgn_mask));
            w[4] = (short)f32_to_bf16(__builtin_bit_cast(float, __builtin_bit_cast(uint32_t, a1.x) ^ sgn_mask));
            w[5] = (short)f32_to_bf16(__builtin_bit_cast(float, __builtin_bit_cast(uint32_t, a1.y) ^ sgn_mask));
            w[6] = (short)f32_to_bf16(__builtin_bit_cast(float, __builtin_bit_cast(uint32_t, a1.z) ^ sgn_mask));
            w[7] = (short)f32_to_bf16(__builtin_bit_cast(float, __builtin_bit_cast(uint32_t, a1.w) ^ sgn_mask));
            int jg = (ac >> 3) + c;
            *(bf16x8*)(ldsA + (ar * 8 + (jg ^ (ar & 7))) * 8) = w;
        }
        __syncthreads();
#pragma unroll
        for (int ks = 0; ks < 2; ks++) {
            bf16x8 af[4], bfr[4];
#pragma unroll
            for (int i = 0; i < 4; i++) {
                int r = wm * 64 + i * 16 + l16;
                af[i] = *(const bf16x8*)(ldsA + (r * 8 + ((ks * 4 + quad) ^ (r & 7))) * 8);
            }
#pragma unroll
            for (int j = 0; j < 4; j++) {
                int r = wn * 64 + j * 16 + l16;
                bfr[j] = *(const bf16x8*)(ldsB + (r * 8 + ((ks * 4 + quad) ^ (r & 7))) * 8);
            }
#pragma unroll
            for (int i = 0; i < 4; i++)
#pragma unroll
                for (int j = 0; j < 4; j++)
                    acc[i][j] = __builtin_amdgcn_mfma_f32_16x16x32_bf16(af[i], bfr[j], acc[i][j], 0, 0, 0);
        }
    }

    float* P = partials + ((size_t)bz << 20);
    const int gm = bm * 128 + wm * 64, gn = bn * 128 + wn * 64;
#pragma unroll
    for (int i = 0; i < 4; i++)
#pragma unroll
        for (int j = 0; j < 4; j++) {
            int col = gn + j * 16 + l16;
#pragma unroll
            for (int r = 0; r < 4; r++)
                P[(size_t)(gm + i * 16 + quad * 4 + r) * 1024 + col] = acc[i][j][r];
        }
}

// ---------------- main GEMM (unchanged from R4: 59 us, 873 TF, m97 plateau) ----------------
// out[8192,1024] = [x_bf | hp_bf] @ [Wmain | Cwbf]^T, two K-phases, 128x128, BK=64.
// 1D grid of 512; bm = id&63 so the 8 blocks sharing an A-tile share id%8 (same XCD).

__global__ __launch_bounds__(256)
void gemm_main_kernel(const u16* __restrict__ Axb, const u16* __restrict__ Ahb,
                      const u16* __restrict__ Bw,  const u16* __restrict__ Bcw,
                      float* __restrict__ out)
{
    __shared__ __align__(16) u16 ldsA[128 * 64];
    __shared__ __align__(16) u16 ldsB[128 * 64];

    const int tid = threadIdx.x, wid = tid >> 6, lane = tid & 63;
    const int quad = lane >> 4, l16 = lane & 15;
    const int wm = wid >> 1, wn = wid & 1;
    const int id = blockIdx.x;
    const int bm = id & 63, bn = id >> 6;

    int srow[4], sj[4];
    u16 *lA[4], *lB[4];
#pragma unroll
    for (int t = 0; t < 4; t++) {
        int s = wid * 256 + t * 64 + lane;
        srow[t] = s >> 3;
        sj[t] = (s & 7) ^ (srow[t] & 7);
        lA[t] = ldsA + s * 8;
        lB[t] = ldsB + s * 8;
    }

    const f32x4 fz = {0.f, 0.f, 0.f, 0.f};
    f32x4 acc[4][4];
#pragma unroll
    for (int i = 0; i < 4; i++)
#pragma unroll
        for (int j = 0; j < 4; j++) acc[i][j] = fz;

#pragma unroll 1
    for (int phase = 0; phase < 2; phase++) {
        const u16* Ap = phase ? Ahb : Axb;
        const u16* Bp = phase ? Bcw : Bw;
        const int KS = phase ? 2048 : 1024;
        const u16* gA[4]; const u16* gB[4];
#pragma unroll
        for (int t = 0; t < 4; t++) {
            gA[t] = Ap + (size_t)(bm * 128 + srow[t]) * KS + sj[t] * 8;
            gB[t] = Bp + (size_t)(bn * 128 + srow[t]) * KS + sj[t] * 8;
        }
        for (int k0 = 0; k0 < KS; k0 += 64) {
            __syncthreads();
#pragma unroll
            for (int t = 0; t < 4; t++) {
                gld_lds16(gA[t] + k0, lA[t]);
                gld_lds16(gB[t] + k0, lB[t]);
            }
            __syncthreads();
#pragma unroll
            for (int ks = 0; ks < 2; ks++) {
                bf16x8 af[4], bfr[4];
#pragma unroll
                for (int i = 0; i < 4; i++) {
                    int r = wm * 64 + i * 16 + l16;
                    af[i] = *(const bf16x8*)(ldsA + (r * 8 + ((ks * 4 + quad) ^ (r & 7))) * 8);
                }
#pragma unroll
                for (int j = 0; j < 4; j++) {
                    int r = wn * 64 + j * 16 + l16;
                    bfr[j] = *(const bf16x8*)(ldsB + (r * 8 + ((ks * 4 + quad) ^ (r & 7))) * 8);
                }
#pragma unroll
                for (int i = 0; i < 4; i++)
#pragma unroll
                    for (int j = 0; j < 4; j++)
                        acc[i][j] = __builtin_amdgcn_mfma_f32_16x16x32_bf16(af[i], bfr[j], acc[i][j], 0, 0, 0);
            }
        }
    }

    const int gm = bm * 128 + wm * 64, gn = bn * 128 + wn * 64;
#pragma unroll
    for (int i = 0; i < 4; i++)
#pragma unroll
        for (int j = 0; j < 4; j++) {
            int col = gn + j * 16 + l16;
#pragma unroll
            for (int r = 0; r < 4; r++)
                out[(size_t)(gm + i * 16 + quad * 4 + r) * 1024 + col] = acc[i][j][r];
        }
}

// ---------------- launch ----------------

extern "C" void kernel_launch(void* const* d_in, const int* in_sizes, int n_in,
                              void* d_out, int out_size, void* d_ws, size_t ws_size,
                              hipStream_t stream)
{
    const float* x      = (const float*)d_in[0];
    const float* h_prev = (const float*)d_in[1];
    const float* Br     = (const float*)d_in[2];
    const float* Bi     = (const float*)d_in[3];
    const float* Cr     = (const float*)d_in[4];
    const float* Ci     = (const float*)d_in[5];
    const float* v_log  = (const float*)d_in[6];
    const float* th_log = (const float*)d_in[7];
    float* out = (float*)d_out;

    const size_t MB = 1024 * 1024;
    // disjoint layout (94 MB): no aliasing, 4-kernel chain
    size_t need = 94 * MB;
    if (ws_size < need) return;

    char* ws = (char*)d_ws;
    u16*   xh_bf    = (u16*)ws;                   // [8192][3072-as-two-blocks]: x_bf 16MB | hp_bf 32MB
    u16*   x_bf     = xh_bf;                      // [8192,1024] bf16
    u16*   hp_bf    = (u16*)(ws + 16 * MB);       // [8192,2048] bf16
    u16*   Bcat     = (u16*)(ws + 48 * MB);       // [1024,4096] bf16 = [BrT|BiT]
    float* partials = (float*)(ws + 56 * MB);     // [8][1024][1024] f32
    u16*   Wmain    = (u16*)(ws + 88 * MB);       // [1024,1024] bf16
    u16*   Cwbf     = (u16*)(ws + 90 * MB);       // [1024,2048] bf16

    // 1) cast x,h_prev -> bf16 AND build Bcat transpose (independent jobs, one kernel)
    bigcast_kernel<<<28672, 256, 0, stream>>>(x, h_prev, Br, Bi, xh_bf, Bcat);
    // 2) partials = [Cr|-Ci] @ Bcat^T (split-K=8, A cast fused in staging)
    gemm_splitk_kernel<<<dim3(8, 8, 8), 256, 0, stream>>>(Cr, Ci, Bcat, partials);
    // 3) Wmain = bf16(sum partials); Cwbf = bf16(Cr*wr - Ci*wi), w inline
    reduce_cw_kernel<<<3072, 256, 0, stream>>>(partials, Cr, Ci, v_log, th_log, Wmain, Cwbf);
    // 4) out = [x_bf | hp_bf] @ [Wmain | Cwbf]^T
    gemm_main_kernel<<<512, 256, 0, stream>>>(x_bf, hp_bf, Wmain, Cwbf, out);
}